// Round 2
// baseline (44659.039 us; speedup 1.0000x reference)
//
#include <hip/hip_runtime.h>

#define B 64
#define T 2048
#define D 128
#define H 256
#define H2 512

__device__ __forceinline__ float sigmoid_f(float x) {
    return 1.f / (1.f + __expf(-x));
}
__device__ __forceinline__ float tanh_f(float x) {
    float e = __expf(2.f * x);          // overflow -> inf -> 1; underflow -> 0 -> -1
    return 1.f - 2.f / (e + 1.f);
}

// One block per batch row, 1024 threads, full T loop. All math fp32.
// Weights streamed from L2 (2.5 MB/step/CU); state in LDS.
__global__ __launch_bounds__(1024) void scan_kernel(
    const float* __restrict__ x,
    const float* __restrict__ Wi, const float* __restrict__ bi,
    const float* __restrict__ Wf, const float* __restrict__ bf,
    const float* __restrict__ Wc, const float* __restrict__ bc,
    const float* __restrict__ Wo, const float* __restrict__ bo,
    const float* __restrict__ Ui, const float* __restrict__ Uf,
    const float* __restrict__ Uc, const float* __restrict__ Uo,
    const float* __restrict__ K1, const float* __restrict__ kb1,
    const float* __restrict__ K2, const float* __restrict__ kb2,
    const float* __restrict__ gamma, const float* __restrict__ beta,
    float* __restrict__ out)
{
    const int b   = blockIdx.x;
    const int tid = threadIdx.x;

    __shared__ float hs[H], cs[H], gos[H], ts[H2], xbuf[D];
    __shared__ float pGf[4][H * 4];   // gate partials   [kq][ (g*64+jj)*4 + c ]
    __shared__ float p1f[8][H2];      // K1 partials     [kq][m]
    __shared__ float p2f[16][H];      // K2 partials     [kq][j]

    if (tid < H) { hs[tid] = 0.f; cs[tid] = 0.f; }

    // ---- phase G roles: q = k-quarter, (g, j4) = gate column group ----
    const int qG   = tid >> 8;        // 0..3
    const int grpG = tid & 255;
    const int gG   = grpG >> 6;       // gate 0..3 (wave-uniform)
    const int j4G  = (grpG & 63) * 4;
    const float* Ug = (gG == 0) ? Ui : (gG == 1) ? Uf : (gG == 2) ? Uc : Uo;
    const float* Wg = (gG == 0) ? Wi : (gG == 1) ? Wf : (gG == 2) ? Wc : Wo;
    const float* UpG = Ug + (size_t)(qG * 64) * H + j4G;   // 64 k rows
    const float* WpG = Wg + (size_t)(qG * 32) * H + j4G;   // 32 d rows

    // ---- phase K1 roles ----
    const int q1 = tid >> 7;          // 0..7
    const int m4 = (tid & 127) * 4;
    const float* K1p = K1 + (size_t)(q1 * 32) * H2 + m4;   // 32 k rows

    // ---- phase K2 roles ----
    const int q2  = tid >> 6;         // 0..15
    const int j4K = (tid & 63) * 4;
    const float* K2p = K2 + (size_t)(q2 * 32) * H + j4K;   // 32 k rows

    // ---- per-role constant preloads ----
    float kb1r = 0.f;
    if (tid < H2) kb1r = kb1[tid];
    float4 bi4, bf4, bc4, bo4, kb24, gam4, bet4;
    if (tid < 64) {
        bi4  = *(const float4*)(bi  + tid * 4);
        bf4  = *(const float4*)(bf  + tid * 4);
        bc4  = *(const float4*)(bc  + tid * 4);
        bo4  = *(const float4*)(bo  + tid * 4);
        kb24 = *(const float4*)(kb2 + tid * 4);
        gam4 = *(const float4*)(gamma + tid * 4);
        bet4 = *(const float4*)(beta  + tid * 4);
    }

    const float* xrow = x + (size_t)b * T * D;
    float* yb = out + (size_t)b * T * H;

    for (int t = 0; t < T; ++t) {
        if (tid < D) xbuf[tid] = xrow[(size_t)t * D + tid];
        __syncthreads();  // xbuf ready; hs from previous step ready

        // ---- phase G partials: preact(g, j4..j4+3) over this thread's k-quarter ----
        {
            float4 a = make_float4(0.f, 0.f, 0.f, 0.f);
            #pragma unroll 4
            for (int k4 = 0; k4 < 16; ++k4) {
                float4 hv = *(const float4*)&hs[qG * 64 + k4 * 4];
                float4 w0 = *(const float4*)(UpG + (size_t)(k4 * 4 + 0) * H);
                float4 w1 = *(const float4*)(UpG + (size_t)(k4 * 4 + 1) * H);
                float4 w2 = *(const float4*)(UpG + (size_t)(k4 * 4 + 2) * H);
                float4 w3 = *(const float4*)(UpG + (size_t)(k4 * 4 + 3) * H);
                a.x = fmaf(hv.x, w0.x, a.x); a.y = fmaf(hv.x, w0.y, a.y);
                a.z = fmaf(hv.x, w0.z, a.z); a.w = fmaf(hv.x, w0.w, a.w);
                a.x = fmaf(hv.y, w1.x, a.x); a.y = fmaf(hv.y, w1.y, a.y);
                a.z = fmaf(hv.y, w1.z, a.z); a.w = fmaf(hv.y, w1.w, a.w);
                a.x = fmaf(hv.z, w2.x, a.x); a.y = fmaf(hv.z, w2.y, a.y);
                a.z = fmaf(hv.z, w2.z, a.z); a.w = fmaf(hv.z, w2.w, a.w);
                a.x = fmaf(hv.w, w3.x, a.x); a.y = fmaf(hv.w, w3.y, a.y);
                a.z = fmaf(hv.w, w3.z, a.z); a.w = fmaf(hv.w, w3.w, a.w);
            }
            #pragma unroll 4
            for (int d4 = 0; d4 < 8; ++d4) {
                float4 xv = *(const float4*)&xbuf[qG * 32 + d4 * 4];
                float4 w0 = *(const float4*)(WpG + (size_t)(d4 * 4 + 0) * H);
                float4 w1 = *(const float4*)(WpG + (size_t)(d4 * 4 + 1) * H);
                float4 w2 = *(const float4*)(WpG + (size_t)(d4 * 4 + 2) * H);
                float4 w3 = *(const float4*)(WpG + (size_t)(d4 * 4 + 3) * H);
                a.x = fmaf(xv.x, w0.x, a.x); a.y = fmaf(xv.x, w0.y, a.y);
                a.z = fmaf(xv.x, w0.z, a.z); a.w = fmaf(xv.x, w0.w, a.w);
                a.x = fmaf(xv.y, w1.x, a.x); a.y = fmaf(xv.y, w1.y, a.y);
                a.z = fmaf(xv.y, w1.z, a.z); a.w = fmaf(xv.y, w1.w, a.w);
                a.x = fmaf(xv.z, w2.x, a.x); a.y = fmaf(xv.z, w2.y, a.y);
                a.z = fmaf(xv.z, w2.z, a.z); a.w = fmaf(xv.z, w2.w, a.w);
                a.x = fmaf(xv.w, w3.x, a.x); a.y = fmaf(xv.w, w3.y, a.y);
                a.z = fmaf(xv.w, w3.z, a.z); a.w = fmaf(xv.w, w3.w, a.w);
            }
            *(float4*)&pGf[qG][grpG * 4] = a;
        }
        __syncthreads();

        // ---- combine gates + cell update (one wave, 4 cols/lane) ----
        if (tid < 64) {
            float4 acts[4];
            #pragma unroll
            for (int g = 0; g < 4; ++g) {
                const int grp4 = (g * 64 + tid) * 4;
                float4 s0 = *(float4*)&pGf[0][grp4];
                float4 s1 = *(float4*)&pGf[1][grp4];
                float4 s2 = *(float4*)&pGf[2][grp4];
                float4 s3 = *(float4*)&pGf[3][grp4];
                float4 bb = (g == 0) ? bi4 : (g == 1) ? bf4 : (g == 2) ? bc4 : bo4;
                float4 s;
                s.x = s0.x + s1.x + s2.x + s3.x + bb.x;
                s.y = s0.y + s1.y + s2.y + s3.y + bb.y;
                s.z = s0.z + s1.z + s2.z + s3.z + bb.z;
                s.w = s0.w + s1.w + s2.w + s3.w + bb.w;
                if (g == 2) {
                    s.x = tanh_f(s.x); s.y = tanh_f(s.y);
                    s.z = tanh_f(s.z); s.w = tanh_f(s.w);
                } else {
                    s.x = sigmoid_f(s.x); s.y = sigmoid_f(s.y);
                    s.z = sigmoid_f(s.z); s.w = sigmoid_f(s.w);
                }
                acts[g] = s;
            }
            float4 c = *(float4*)&cs[tid * 4];
            c.x = fmaf(acts[1].x, c.x, acts[0].x * acts[2].x);
            c.y = fmaf(acts[1].y, c.y, acts[0].y * acts[2].y);
            c.z = fmaf(acts[1].z, c.z, acts[0].z * acts[2].z);
            c.w = fmaf(acts[1].w, c.w, acts[0].w * acts[2].w);
            *(float4*)&cs[tid * 4]  = c;
            *(float4*)&gos[tid * 4] = acts[3];
        }
        __syncthreads();

        // ---- phase K1 partials: ts_pre(m4..m4+3) over 32-k slice ----
        {
            float4 a = make_float4(0.f, 0.f, 0.f, 0.f);
            #pragma unroll 4
            for (int k4 = 0; k4 < 8; ++k4) {
                float4 cv = *(const float4*)&cs[q1 * 32 + k4 * 4];
                float4 w0 = *(const float4*)(K1p + (size_t)(k4 * 4 + 0) * H2);
                float4 w1 = *(const float4*)(K1p + (size_t)(k4 * 4 + 1) * H2);
                float4 w2 = *(const float4*)(K1p + (size_t)(k4 * 4 + 2) * H2);
                float4 w3 = *(const float4*)(K1p + (size_t)(k4 * 4 + 3) * H2);
                a.x = fmaf(cv.x, w0.x, a.x); a.y = fmaf(cv.x, w0.y, a.y);
                a.z = fmaf(cv.x, w0.z, a.z); a.w = fmaf(cv.x, w0.w, a.w);
                a.x = fmaf(cv.y, w1.x, a.x); a.y = fmaf(cv.y, w1.y, a.y);
                a.z = fmaf(cv.y, w1.z, a.z); a.w = fmaf(cv.y, w1.w, a.w);
                a.x = fmaf(cv.z, w2.x, a.x); a.y = fmaf(cv.z, w2.y, a.y);
                a.z = fmaf(cv.z, w2.z, a.z); a.w = fmaf(cv.z, w2.w, a.w);
                a.x = fmaf(cv.w, w3.x, a.x); a.y = fmaf(cv.w, w3.y, a.y);
                a.z = fmaf(cv.w, w3.z, a.z); a.w = fmaf(cv.w, w3.w, a.w);
            }
            *(float4*)&p1f[q1][m4] = a;
        }
        __syncthreads();

        // ---- K1 combine -> ts ----
        if (tid < H2) {
            float s = kb1r;
            #pragma unroll
            for (int q = 0; q < 8; ++q) s += p1f[q][tid];
            ts[tid] = tanh_f(s);
        }
        __syncthreads();

        // ---- phase K2 partials: h_pre(j4..j4+3) over 32-k slice ----
        {
            float4 a = make_float4(0.f, 0.f, 0.f, 0.f);
            #pragma unroll 4
            for (int k4 = 0; k4 < 8; ++k4) {
                float4 tv = *(const float4*)&ts[q2 * 32 + k4 * 4];
                float4 w0 = *(const float4*)(K2p + (size_t)(k4 * 4 + 0) * H);
                float4 w1 = *(const float4*)(K2p + (size_t)(k4 * 4 + 1) * H);
                float4 w2 = *(const float4*)(K2p + (size_t)(k4 * 4 + 2) * H);
                float4 w3 = *(const float4*)(K2p + (size_t)(k4 * 4 + 3) * H);
                a.x = fmaf(tv.x, w0.x, a.x); a.y = fmaf(tv.x, w0.y, a.y);
                a.z = fmaf(tv.x, w0.z, a.z); a.w = fmaf(tv.x, w0.w, a.w);
                a.x = fmaf(tv.y, w1.x, a.x); a.y = fmaf(tv.y, w1.y, a.y);
                a.z = fmaf(tv.y, w1.z, a.z); a.w = fmaf(tv.y, w1.w, a.w);
                a.x = fmaf(tv.z, w2.x, a.x); a.y = fmaf(tv.z, w2.y, a.y);
                a.z = fmaf(tv.z, w2.z, a.z); a.w = fmaf(tv.z, w2.w, a.w);
                a.x = fmaf(tv.w, w3.x, a.x); a.y = fmaf(tv.w, w3.y, a.y);
                a.z = fmaf(tv.w, w3.z, a.z); a.w = fmaf(tv.w, w3.w, a.w);
            }
            *(float4*)&p2f[q2][j4K] = a;
        }
        __syncthreads();

        // ---- K2 combine + o*tanh + LayerNorm (one wave, 4 cols/lane) ----
        if (tid < 64) {
            float4 hp = make_float4(0.f, 0.f, 0.f, 0.f);
            #pragma unroll
            for (int q = 0; q < 16; ++q) {
                float4 p = *(float4*)&p2f[q][tid * 4];
                hp.x += p.x; hp.y += p.y; hp.z += p.z; hp.w += p.w;
            }
            hp.x += kb24.x; hp.y += kb24.y; hp.z += kb24.z; hp.w += kb24.w;
            float4 o = *(float4*)&gos[tid * 4];
            float4 u;
            u.x = o.x * tanh_f(hp.x); u.y = o.y * tanh_f(hp.y);
            u.z = o.z * tanh_f(hp.z); u.w = o.w * tanh_f(hp.w);
            float s1 = u.x + u.y + u.z + u.w;
            float s2 = u.x * u.x + u.y * u.y + u.z * u.z + u.w * u.w;
            #pragma unroll
            for (int off = 32; off > 0; off >>= 1) {
                s1 += __shfl_xor(s1, off);
                s2 += __shfl_xor(s2, off);
            }
            float mu   = s1 * (1.f / 256.f);
            float var  = fmaf(-mu, mu, s2 * (1.f / 256.f));
            float rstd = rsqrtf(var + 1e-5f);
            float4 hn;
            hn.x = (u.x - mu) * rstd * gam4.x + bet4.x;
            hn.y = (u.y - mu) * rstd * gam4.y + bet4.y;
            hn.z = (u.z - mu) * rstd * gam4.z + bet4.z;
            hn.w = (u.w - mu) * rstd * gam4.w + bet4.w;
            *(float4*)&hs[tid * 4] = hn;
            *(float4*)(yb + (size_t)t * H + tid * 4) = hn;
            if (t == T - 1) {
                *(float4*)(out + (size_t)B * T * H + (size_t)b * H + tid * 4) = hn;
                float4 c = *(float4*)&cs[tid * 4];
                *(float4*)(out + (size_t)B * T * H + (size_t)B * H + (size_t)b * H + tid * 4) = c;
            }
        }
        // no trailing barrier: next iteration's first __syncthreads protects hs
    }
}

extern "C" void kernel_launch(void* const* d_in, const int* in_sizes, int n_in,
                              void* d_out, int out_size, void* d_ws, size_t ws_size,
                              hipStream_t stream) {
    (void)in_sizes; (void)n_in; (void)out_size; (void)d_ws; (void)ws_size;

    const float* x     = (const float*)d_in[0];
    const float* Wi    = (const float*)d_in[1];
    const float* bi    = (const float*)d_in[2];
    const float* Wf    = (const float*)d_in[3];
    const float* bf    = (const float*)d_in[4];
    const float* Wc    = (const float*)d_in[5];
    const float* bc    = (const float*)d_in[6];
    const float* Wo    = (const float*)d_in[7];
    const float* bo    = (const float*)d_in[8];
    const float* Ui    = (const float*)d_in[9];
    const float* Uf    = (const float*)d_in[10];
    const float* Uc    = (const float*)d_in[11];
    const float* Uo    = (const float*)d_in[12];
    const float* K1    = (const float*)d_in[13];
    const float* kb1   = (const float*)d_in[14];
    const float* K2    = (const float*)d_in[15];
    const float* kb2   = (const float*)d_in[16];
    const float* gamma = (const float*)d_in[17];
    const float* beta  = (const float*)d_in[18];
    float* out = (float*)d_out;

    scan_kernel<<<dim3(B), dim3(1024), 0, stream>>>(
        x, Wi, bi, Wf, bf, Wc, bc, Wo, bo,
        Ui, Uf, Uc, Uo, K1, kb1, K2, kb2, gamma, beta, out);
}